// Round 5
// baseline (108.388 us; speedup 1.0000x reference)
//
#include <hip/hip_runtime.h>

#define SLOPE 0.2f

__device__ __forceinline__ float leaky(float v) {
    // slope < 1  =>  leaky(v) == max(v, 0.2*v)
    return __builtin_fmaxf(v, SLOPE * v);
}

__device__ __forceinline__ float fast_tanh(float v) {
    // tanh(x) = 1 - 2/(exp(2x)+1); saturates correctly at +/-1.
    float e = __expf(2.0f * v);
    return 1.0f - 2.0f * __builtin_amdgcn_rcpf(e + 1.0f);
}

// Exchange with paired lane (lane ^ 1) via DPP quad_perm [1,0,3,2].
// MUST be called under full EXEC (never inside a divergent branch/ternary):
// with bound_ctrl=1 a read from an EXEC-disabled source lane returns 0,
// which silently zeroes the halo (R4's failure mode).
__device__ __forceinline__ float swap1(float v) {
    int i = __builtin_bit_cast(int, v);
    i = __builtin_amdgcn_mov_dpp(i, 0xB1, 0xF, 0xF, true);
    return __builtin_bit_cast(float, i);
}

// 2 threads per sample (even lane = left half, odd = right half of every
// layer's length dim). Halo values cross lanes via swap1, computed
// UNCONDITIONALLY and then selected with p (v_cndmask, no divergence).
// Convs index e1h/bnh/skh directly with compile-time u -> minimal live VGPRs.
// __launch_bounds__(256,4): VGPR cap 128, no scratch spills (R3's (256,6)
// 85-VGPR cap forced spills and made the 2-way split neutral).
__global__ __launch_bounds__(256, 4) void minigen_kernel(
    const float* __restrict__ x,
    const float* __restrict__ w1, const float* __restrict__ b1,
    const float* __restrict__ w2, const float* __restrict__ b2,
    const float* __restrict__ w3, const float* __restrict__ b3,
    const float* __restrict__ w4, const float* __restrict__ b4,
    float* __restrict__ out)
{
    __shared__ float4 lds[128 * 9];              // 128 samples x (8 f4 + pad)

    const int t = threadIdx.x;
    const int p = t & 1;                          // which half of the sample
    const int row = t >> 1;                       // local sample row in LDS
    const long long blockBase = (long long)blockIdx.x * 1024;  // f4 units

    // ---- stage in: coalesced global -> LDS (1024 f4 per block) ----
    const float4* xin = (const float4*)x;
#pragma unroll
    for (int q = 0; q < 4; ++q) {
        int g = q * 256 + t;
        float4 v = xin[blockBase + g];
        lds[(g >> 3) * 9 + (g & 7)] = v;
    }
    __syncthreads();

    // ---- own half: x[ic][p*8 + j], j=0..7 ----
    float xr[2][8];
#pragma unroll
    for (int ic = 0; ic < 2; ++ic) {
#pragma unroll
        for (int m = 0; m < 2; ++m) {
            float4 v = lds[row * 9 + ic * 4 + p * 2 + m];
            xr[ic][4*m+0] = v.x; xr[ic][4*m+1] = v.y;
            xr[ic][4*m+2] = v.z; xr[ic][4*m+3] = v.w;
        }
    }

    // ---- conv1: [2,16] -> [4,8], stride 2, pad 1, leaky ----
    float xl[2];                                  // left halo (or pad)
#pragma unroll
    for (int ic = 0; ic < 2; ++ic) {
        float h = swap1(xr[ic][7]);               // full-EXEC DPP
        xl[ic] = p ? h : 0.0f;                    // select AFTER
    }

    float e1h[4][4];                              // e1[oc][p*4 + l]
#pragma unroll
    for (int oc = 0; oc < 4; ++oc) {
#pragma unroll
        for (int l = 0; l < 4; ++l) {
            float s = b1[oc];
#pragma unroll
            for (int ic = 0; ic < 2; ++ic)
#pragma unroll
                for (int k = 0; k < 3; ++k) {
                    int u = 2*l - 1 + k;          // [-1..7], compile-time
                    float v = (u < 0) ? xl[ic] : xr[ic][u];
                    s = fmaf(v, w1[(oc*2 + ic)*3 + k], s);
                }
            e1h[oc][l] = leaky(s);
        }
    }

    // ---- conv2: [4,8] -> [8,4], stride 2, pad 1, leaky ----
    float el[4];
#pragma unroll
    for (int ic = 0; ic < 4; ++ic) {
        float h = swap1(e1h[ic][3]);
        el[ic] = p ? h : 0.0f;
    }

    float bnh[8][2];                              // bn[oc][p*2 + l]
#pragma unroll
    for (int oc = 0; oc < 8; ++oc) {
#pragma unroll
        for (int l = 0; l < 2; ++l) {
            float s = b2[oc];
#pragma unroll
            for (int ic = 0; ic < 4; ++ic)
#pragma unroll
                for (int k = 0; k < 3; ++k) {
                    int u = 2*l - 1 + k;          // [-1..3]
                    float v = (u < 0) ? el[ic] : e1h[ic][u];
                    s = fmaf(v, w2[(oc*4 + ic)*3 + k], s);
                }
            bnh[oc][l] = leaky(s);
        }
    }

    // ---- up1(x2) + conv3: [8,8] -> [4,8], s1 p1, leaky, + skip e1 ----
    // up1 window pos u = l-1+k in [-1..4]; u==-1 -> bl, u==4 -> br,
    // else bnh[ic][u>>1].
    float bl[8], br[8];
#pragma unroll
    for (int ic = 0; ic < 8; ++ic) {
        float hL = swap1(bnh[ic][1]);             // p=1 needs bn[1] (even lane)
        float hR = swap1(bnh[ic][0]);             // p=0 needs bn[2] (odd lane)
        bl[ic] = p ? hL : 0.0f;
        br[ic] = p ? 0.0f : hR;
    }

    float skh[4][4];                              // sk[oc][p*4 + l]
#pragma unroll
    for (int oc = 0; oc < 4; ++oc) {
#pragma unroll
        for (int l = 0; l < 4; ++l) {
            float s = b3[oc];
#pragma unroll
            for (int ic = 0; ic < 8; ++ic)
#pragma unroll
                for (int k = 0; k < 3; ++k) {
                    int u = l - 1 + k;            // [-1..4]
                    float v = (u < 0) ? bl[ic]
                            : (u > 3) ? br[ic]
                            : bnh[ic][u >> 1];
                    s = fmaf(v, w3[(oc*8 + ic)*3 + k], s);
                }
            skh[oc][l] = leaky(s) + e1h[oc][l];
        }
    }

    // ---- up2(x2) + conv4: [4,16] -> [2,16], s1 p1, tanh ----
    float sl[4], sr[4];
#pragma unroll
    for (int ic = 0; ic < 4; ++ic) {
        float hL = swap1(skh[ic][3]);             // p=1 needs sk[3] (even lane)
        float hR = swap1(skh[ic][0]);             // p=0 needs sk[4] (odd lane)
        sl[ic] = p ? hL : 0.0f;
        sr[ic] = p ? 0.0f : hR;
    }

    float oh[2][8];                               // out[oc][p*8 + l]
#pragma unroll
    for (int oc = 0; oc < 2; ++oc) {
#pragma unroll
        for (int l = 0; l < 8; ++l) {
            float s = b4[oc];
#pragma unroll
            for (int ic = 0; ic < 4; ++ic)
#pragma unroll
                for (int k = 0; k < 3; ++k) {
                    int u = l - 1 + k;            // [-1..8]
                    float v = (u < 0) ? sl[ic]
                            : (u > 7) ? sr[ic]
                            : skh[ic][u >> 1];
                    s = fmaf(v, w4[(oc*4 + ic)*3 + k], s);
                }
            oh[oc][l] = fast_tanh(s);
        }
    }

    // ---- own slots back to LDS (same slots this thread read) ----
#pragma unroll
    for (int oc = 0; oc < 2; ++oc)
#pragma unroll
        for (int m = 0; m < 2; ++m)
            lds[row * 9 + oc * 4 + p * 2 + m] =
                make_float4(oh[oc][4*m+0], oh[oc][4*m+1],
                            oh[oc][4*m+2], oh[oc][4*m+3]);
    __syncthreads();

    // ---- stage out: LDS -> coalesced global ----
    float4* op = (float4*)out;
#pragma unroll
    for (int q = 0; q < 4; ++q) {
        int g = q * 256 + t;
        op[blockBase + g] = lds[(g >> 3) * 9 + (g & 7)];
    }
}

extern "C" void kernel_launch(void* const* d_in, const int* in_sizes, int n_in,
                              void* d_out, int out_size, void* d_ws, size_t ws_size,
                              hipStream_t stream) {
    const float* x  = (const float*)d_in[0];
    const float* w1 = (const float*)d_in[1];
    const float* b1 = (const float*)d_in[2];
    const float* w2 = (const float*)d_in[3];
    const float* b2 = (const float*)d_in[4];
    const float* w3 = (const float*)d_in[5];
    const float* b3 = (const float*)d_in[6];
    const float* w4 = (const float*)d_in[7];
    const float* b4 = (const float*)d_in[8];
    float* out = (float*)d_out;

    int n = in_sizes[0] / 32;           // B = 262144 samples, 128 per block
    int grid = n / 128;                  // exact: 262144 % 128 == 0
    hipLaunchKernelGGL(minigen_kernel, dim3(grid), dim3(256), 0, stream,
                       x, w1, b1, w2, b2, w3, b3, w4, b4, out);
}

// Round 6
// 104.765 us; speedup vs baseline: 1.0346x; 1.0346x over previous
//
#include <hip/hip_runtime.h>

typedef float v2f __attribute__((ext_vector_type(2)));

#define SLOPE 0.2f

// v_pk_max_f32: leaky(v) == max(v, 0.2v) elementwise
static __device__ __forceinline__ v2f leaky2(v2f v) {
    return __builtin_elementwise_max(v, SLOPE * v);
}

// v_pk_fma_f32
static __device__ __forceinline__ v2f fma2(v2f a, v2f b, v2f c) {
    return __builtin_elementwise_fma(a, b, c);
}

static __device__ __forceinline__ float fast_tanh(float v) {
    // tanh(x) = 1 - 2/(exp(2x)+1); saturates correctly at +/-1.
    float e = __expf(2.0f * v);
    return 1.0f - 2.0f * __builtin_amdgcn_rcpf(e + 1.0f);
}

// 1 thread per sample; all four convs packed 2-wide over OUTPUT channels
// (v_pk_fma_f32). Accumulator layout chains: e1p (oc-pairs) is consumed by
// conv2/conv3 via half-extracts (op_sel) and by the skip-add directly.
// LDS-staged coalesced global I/O as in R2 (the structure that took the
// kernel 43.5 -> ~30 us); this round attacks the invariant that kept
// R2/R3/R5 all at ~30 us: total VALU instruction count.
__global__ __launch_bounds__(256, 4) void minigen_kernel(
    const float* __restrict__ x,
    const float* __restrict__ w1, const float* __restrict__ b1,
    const float* __restrict__ w2, const float* __restrict__ b2,
    const float* __restrict__ w3, const float* __restrict__ b3,
    const float* __restrict__ w4, const float* __restrict__ b4,
    float* __restrict__ out)
{
    __shared__ float4 lds[256 * 9];              // 256 samples x (8 f4 + pad)

    const int t = threadIdx.x;
    const int blockBase = blockIdx.x * 2048;     // f4 units; 2M f4 fits int

    // ---- stage in: coalesced global -> LDS (2048 f4 per block) ----
    const float4* xin = (const float4*)x;
#pragma unroll
    for (int q = 0; q < 8; ++q) {
        int g = q * 256 + t;
        lds[(g >> 3) * 9 + (g & 7)] = xin[blockBase + g];
    }
    __syncthreads();

    // ---- own sample: LDS -> registers, x[2][16] ----
    float xr[2][16];
#pragma unroll
    for (int m = 0; m < 8; ++m) {
        float4 v = lds[t * 9 + m];
        int c = m >> 2, base = (m & 3) * 4;
        xr[c][base+0] = v.x; xr[c][base+1] = v.y;
        xr[c][base+2] = v.z; xr[c][base+3] = v.w;
    }

    // ---- conv1: [2,16] -> [4,8], s2 p1, leaky; oc-pairs {2cp,2cp+1} ----
    v2f e1p[2][8];
#pragma unroll
    for (int cp = 0; cp < 2; ++cp) {
#pragma unroll
        for (int l = 0; l < 8; ++l) {
            v2f s = { b1[2*cp], b1[2*cp+1] };
#pragma unroll
            for (int ic = 0; ic < 2; ++ic)
#pragma unroll
                for (int k = 0; k < 3; ++k) {
                    int u = 2*l - 1 + k;          // [-1..15], compile-time
                    if (u >= 0) {
                        v2f w = { w1[((2*cp)*2 + ic)*3 + k],
                                  w1[((2*cp+1)*2 + ic)*3 + k] };
                        float xv = xr[ic][u];
                        s = fma2(w, (v2f){xv, xv}, s);
                    }
                }
            e1p[cp][l] = leaky2(s);
        }
    }

    // ---- conv2: [4,8] -> [8,4], s2 p1, leaky ----
    v2f bnp[4][4];
#pragma unroll
    for (int cp = 0; cp < 4; ++cp) {
#pragma unroll
        for (int l = 0; l < 4; ++l) {
            v2f s = { b2[2*cp], b2[2*cp+1] };
#pragma unroll
            for (int ic = 0; ic < 4; ++ic)
#pragma unroll
                for (int k = 0; k < 3; ++k) {
                    int u = 2*l - 1 + k;          // [-1..7]
                    if (u >= 0) {
                        float ev = (ic & 1) ? e1p[ic>>1][u].y
                                            : e1p[ic>>1][u].x;
                        v2f w = { w2[((2*cp)*4 + ic)*3 + k],
                                  w2[((2*cp+1)*4 + ic)*3 + k] };
                        s = fma2(w, (v2f){ev, ev}, s);
                    }
                }
            bnp[cp][l] = leaky2(s);
        }
    }

    // ---- up1(x2) + conv3: [8,8] -> [4,8], s1 p1, leaky, + skip e1 ----
    v2f skp[2][8];
#pragma unroll
    for (int cp = 0; cp < 2; ++cp) {
#pragma unroll
        for (int l = 0; l < 8; ++l) {
            v2f s = { b3[2*cp], b3[2*cp+1] };
#pragma unroll
            for (int ic = 0; ic < 8; ++ic)
#pragma unroll
                for (int k = 0; k < 3; ++k) {
                    int u = l - 1 + k;            // [-1..8]
                    if (u >= 0 && u < 8) {
                        int j = u >> 1;           // up1: nearest x2
                        float bv = (ic & 1) ? bnp[ic>>1][j].y
                                            : bnp[ic>>1][j].x;
                        v2f w = { w3[((2*cp)*8 + ic)*3 + k],
                                  w3[((2*cp+1)*8 + ic)*3 + k] };
                        s = fma2(w, (v2f){bv, bv}, s);
                    }
                }
            skp[cp][l] = leaky2(s) + e1p[cp][l];  // pair layouts match
        }
    }

    // ---- up2(x2) + conv4: [4,16] -> [2,16], s1 p1, tanh; oc-pair {0,1} ----
    v2f op4[16];
#pragma unroll
    for (int l = 0; l < 16; ++l) {
        v2f s = { b4[0], b4[1] };
#pragma unroll
        for (int ic = 0; ic < 4; ++ic)
#pragma unroll
            for (int k = 0; k < 3; ++k) {
                int u = l - 1 + k;                // [-1..16]
                if (u >= 0 && u < 16) {
                    int j = u >> 1;               // up2: nearest x2
                    float sv = (ic & 1) ? skp[ic>>1][j].y
                                        : skp[ic>>1][j].x;
                    v2f w = { w4[(0*4 + ic)*3 + k],
                              w4[(1*4 + ic)*3 + k] };
                    s = fma2(w, (v2f){sv, sv}, s);
                }
            }
        op4[l] = (v2f){ fast_tanh(s.x), fast_tanh(s.y) };
    }

    // ---- own row back to LDS: out[0][0..15] then out[1][0..15] ----
#pragma unroll
    for (int m = 0; m < 4; ++m) {
        lds[t*9 + m]     = make_float4(op4[4*m+0].x, op4[4*m+1].x,
                                       op4[4*m+2].x, op4[4*m+3].x);
        lds[t*9 + 4 + m] = make_float4(op4[4*m+0].y, op4[4*m+1].y,
                                       op4[4*m+2].y, op4[4*m+3].y);
    }
    __syncthreads();

    // ---- stage out: LDS -> coalesced global ----
    float4* outp = (float4*)out;
#pragma unroll
    for (int q = 0; q < 8; ++q) {
        int g = q * 256 + t;
        outp[blockBase + g] = lds[(g >> 3) * 9 + (g & 7)];
    }
}

extern "C" void kernel_launch(void* const* d_in, const int* in_sizes, int n_in,
                              void* d_out, int out_size, void* d_ws, size_t ws_size,
                              hipStream_t stream) {
    const float* x  = (const float*)d_in[0];
    const float* w1 = (const float*)d_in[1];
    const float* b1 = (const float*)d_in[2];
    const float* w2 = (const float*)d_in[3];
    const float* b2 = (const float*)d_in[4];
    const float* w3 = (const float*)d_in[5];
    const float* b3 = (const float*)d_in[6];
    const float* w4 = (const float*)d_in[7];
    const float* b4 = (const float*)d_in[8];
    float* out = (float*)d_out;

    int n = in_sizes[0] / 32;            // B = 262144 samples, 256 per block
    int grid = n / 256;                  // 1024 blocks, exact
    hipLaunchKernelGGL(minigen_kernel, dim3(grid), dim3(256), 0, stream,
                       x, w1, b1, w2, b2, w3, b3, w4, b4, out);
}